// Round 14
// baseline (242.915 us; speedup 1.0000x reference)
//
#include <hip/hip_runtime.h>

typedef __attribute__((ext_vector_type(8))) short short8;
typedef __attribute__((ext_vector_type(4))) float f32x4;

static __device__ __forceinline__ unsigned short f2bf(float f){
  unsigned u = __float_as_uint(f);
  u += 0x7FFF + ((u >> 16) & 1);
  return (unsigned short)(u >> 16);
}

static __device__ __forceinline__ f32x4 MF(short8 a, short8 b, f32x4 c){
  return __builtin_amdgcn_mfma_f32_16x16x32_bf16(a, b, c, 0, 0, 0);
}

#define GL16(g, l) __builtin_amdgcn_global_load_lds( \
    (const __attribute__((address_space(1))) void*)(g), \
    (__attribute__((address_space(3))) void*)(l), 16, 0, 0)

#define SBAR { __builtin_amdgcn_sched_barrier(0); __builtin_amdgcn_s_barrier(); __builtin_amdgcn_sched_barrier(0); }

// ---------------- fp32 -> bf16 convert (all 4 weights, one launch) ----------------
__global__ __launch_bounds__(256) void cvt_all(
    const float* __restrict__ a0, const float* __restrict__ a1,
    const float* __restrict__ a2, const float* __restrict__ a3,
    unsigned short* __restrict__ o0, unsigned short* __restrict__ o1,
    unsigned short* __restrict__ o2, unsigned short* __restrict__ o3){
  int i = blockIdx.x * 256 + threadIdx.x;
  const float* src; unsigned short* dst; int off;
  if (i < 786432)       { src = a0; dst = o0; off = i; }
  else if (i < 1048576) { src = a1; dst = o1; off = i - 786432; }
  else if (i < 2097152) { src = a2; dst = o2; off = i - 1048576; }
  else                  { src = a3; dst = o3; off = i - 2097152; }
  float4 v = reinterpret_cast<const float4*>(src)[off];
  ushort4 o;
  o.x = f2bf(v.x); o.y = f2bf(v.y); o.z = f2bf(v.z); o.w = f2bf(v.w);
  reinterpret_cast<ushort4*>(dst)[off] = o;
}

// ---------------- LayerNorm fp32 -> bf16 ----------------
__global__ __launch_bounds__(256) void ln_bf16(const float* __restrict__ x,
    const float* __restrict__ g, const float* __restrict__ b,
    unsigned short* __restrict__ out){
  int row = blockIdx.x, t = threadIdx.x;
  const float* xr = x + (size_t)row * 1024;
  float4 xv = reinterpret_cast<const float4*>(xr)[t];
  float s  = xv.x + xv.y + xv.z + xv.w;
  float sq = xv.x*xv.x + xv.y*xv.y + xv.z*xv.z + xv.w*xv.w;
  #pragma unroll
  for (int m = 32; m >= 1; m >>= 1){ s += __shfl_xor(s, m); sq += __shfl_xor(sq, m); }
  __shared__ float ss[4], ssq[4];
  int w = t >> 6, lane = t & 63;
  if (lane == 0){ ss[w] = s; ssq[w] = sq; }
  __syncthreads();
  s  = ss[0] + ss[1] + ss[2] + ss[3];
  sq = ssq[0] + ssq[1] + ssq[2] + ssq[3];
  float mu = s * (1.f/1024.f);
  float rs = rsqrtf(sq * (1.f/1024.f) - mu*mu + 1e-5f);
  float4 gv = reinterpret_cast<const float4*>(g)[t];
  float4 bv = reinterpret_cast<const float4*>(b)[t];
  ushort4 o;
  o.x = f2bf((xv.x - mu) * rs * gv.x + bv.x);
  o.y = f2bf((xv.y - mu) * rs * gv.y + bv.y);
  o.z = f2bf((xv.z - mu) * rs * gv.z + bv.z);
  o.w = f2bf((xv.w - mu) * rs * gv.w + bv.w);
  reinterpret_cast<ushort4*>(out + (size_t)row * 1024)[t] = o;
}

// ---------------- 256x256 8-phase GEMM (m201 template, plain HIP) ----------------
template<int EPI>
__global__ __launch_bounds__(512, 2) void gemm8p(
    const unsigned short* __restrict__ A,
    const unsigned short* __restrict__ B,
    const float* __restrict__ bias,
    void* __restrict__ C,
    int M, int N, int K)
{
  __shared__ __attribute__((aligned(16))) short As[2 * 256 * 64];
  __shared__ __attribute__((aligned(16))) short Bs[2 * 256 * 64];
  const int NT = K >> 6;
  int tid = threadIdx.x, lane = tid & 63, wave = tid >> 6;
  int wm = wave >> 2, wn = wave & 3;
  int l15 = lane & 15, hi = lane >> 4;
  int hi2 = hi ^ (((l15 >> 2) & 1) << 1);
  int bm = blockIdx.y * 256, bn = blockIdx.x * 256;
  int lr = lane >> 3;
  int sg8 = ((lane & 7) ^ ((lane >> 5) << 1)) * 8;
  int rb0 = wave * 16;

  f32x4 acc[8][4] = {};
  short8 aR[4][2], bA[2][2], bB[2][2];

  auto stage = [&](int T, int h){
    if (T >= NT) return;
    const unsigned short* src = (h < 2) ? (A + (size_t)(bm + ((h & 1) << 7)) * K)
                                        : (B + (size_t)(bn + ((h & 1) << 7)) * K);
    short* dst = ((h < 2) ? As : Bs) + ((T & 1) << 14) + ((h & 1) << 13);
    const unsigned short* s = src + (size_t)(rb0 + lr) * K + (T << 6) + sg8;
    GL16(s, dst + rb0 * 64);
    GL16(s + (size_t)8 * K, dst + (rb0 + 8) * 64);
  };
  auto LDA = [&](const short* Ab, int m, int kk){
    int R = wm * 128 + m * 16 + l15;
    return *(const short8*)(Ab + R * 64 + kk * 32 + hi2 * 8);
  };
  auto LDB = [&](const short* Bb, int n, int kk){
    int R = wn * 64 + n * 16 + l15;
    return *(const short8*)(Bb + R * 64 + kk * 32 + hi2 * 8);
  };

  stage(0, 0); stage(0, 1); stage(0, 2); stage(0, 3);
  stage(1, 0); stage(1, 1);
  asm volatile("s_waitcnt vmcnt(4)" ::: "memory");
  SBAR;

  for (int i = 0; i < (NT >> 1); ++i){
    int t0 = 2 * i, t1 = t0 + 1;
    const short* A0 = As;            const short* B0 = Bs;
    const short* A1 = As + 16384;    const short* B1 = Bs + 16384;
    #pragma unroll
    for (int m = 0; m < 4; m++){ aR[m][0] = LDA(A0, m, 0); aR[m][1] = LDA(A0, m, 1); }
    #pragma unroll
    for (int n = 0; n < 2; n++){ bA[n][0] = LDB(B0, n, 0); bA[n][1] = LDB(B0, n, 1); }
    __builtin_amdgcn_sched_barrier(0);
    stage(t1, 2);
    SBAR;
    __builtin_amdgcn_s_setprio(1);
    #pragma unroll
    for (int m = 0; m < 4; m++)
      #pragma unroll
      for (int n = 0; n < 2; n++)
        #pragma unroll
        for (int kk = 0; kk < 2; kk++) acc[m][n] = MF(aR[m][kk], bA[n][kk], acc[m][n]);
    __builtin_amdgcn_s_setprio(0);
    SBAR;
    #pragma unroll
    for (int n = 0; n < 2; n++){ bB[n][0] = LDB(B0, n + 2, 0); bB[n][1] = LDB(B0, n + 2, 1); }
    __builtin_amdgcn_sched_barrier(0);
    stage(t1, 3);
    SBAR;
    __builtin_amdgcn_s_setprio(1);
    #pragma unroll
    for (int m = 0; m < 4; m++)
      #pragma unroll
      for (int n = 0; n < 2; n++)
        #pragma unroll
        for (int kk = 0; kk < 2; kk++) acc[m][n + 2] = MF(aR[m][kk], bB[n][kk], acc[m][n + 2]);
    __builtin_amdgcn_s_setprio(0);
    SBAR;
    #pragma unroll
    for (int m = 0; m < 4; m++){ aR[m][0] = LDA(A0, m + 4, 0); aR[m][1] = LDA(A0, m + 4, 1); }
    __builtin_amdgcn_sched_barrier(0);
    stage(t0 + 2, 0);
    SBAR;
    __builtin_amdgcn_s_setprio(1);
    #pragma unroll
    for (int m = 0; m < 4; m++)
      #pragma unroll
      for (int n = 0; n < 2; n++)
        #pragma unroll
        for (int kk = 0; kk < 2; kk++) acc[m + 4][n] = MF(aR[m][kk], bA[n][kk], acc[m + 4][n]);
    __builtin_amdgcn_s_setprio(0);
    SBAR;
    stage(t0 + 2, 1);
    SBAR;
    __builtin_amdgcn_s_setprio(1);
    #pragma unroll
    for (int m = 0; m < 4; m++)
      #pragma unroll
      for (int n = 0; n < 2; n++)
        #pragma unroll
        for (int kk = 0; kk < 2; kk++) acc[m + 4][n + 2] = MF(aR[m][kk], bB[n][kk], acc[m + 4][n + 2]);
    __builtin_amdgcn_s_setprio(0);
    asm volatile("s_waitcnt vmcnt(4)" ::: "memory");
    SBAR;
    #pragma unroll
    for (int m = 0; m < 4; m++){ aR[m][0] = LDA(A1, m, 0); aR[m][1] = LDA(A1, m, 1); }
    #pragma unroll
    for (int n = 0; n < 2; n++){ bA[n][0] = LDB(B1, n, 0); bA[n][1] = LDB(B1, n, 1); }
    __builtin_amdgcn_sched_barrier(0);
    stage(t0 + 2, 2);
    SBAR;
    __builtin_amdgcn_s_setprio(1);
    #pragma unroll
    for (int m = 0; m < 4; m++)
      #pragma unroll
      for (int n = 0; n < 2; n++)
        #pragma unroll
        for (int kk = 0; kk < 2; kk++) acc[m][n] = MF(aR[m][kk], bA[n][kk], acc[m][n]);
    __builtin_amdgcn_s_setprio(0);
    SBAR;
    #pragma unroll
    for (int n = 0; n < 2; n++){ bB[n][0] = LDB(B1, n + 2, 0); bB[n][1] = LDB(B1, n + 2, 1); }
    __builtin_amdgcn_sched_barrier(0);
    stage(t0 + 2, 3);
    SBAR;
    __builtin_amdgcn_s_setprio(1);
    #pragma unroll
    for (int m = 0; m < 4; m++)
      #pragma unroll
      for (int n = 0; n < 2; n++)
        #pragma unroll
        for (int kk = 0; kk < 2; kk++) acc[m][n + 2] = MF(aR[m][kk], bB[n][kk], acc[m][n + 2]);
    __builtin_amdgcn_s_setprio(0);
    SBAR;
    #pragma unroll
    for (int m = 0; m < 4; m++){ aR[m][0] = LDA(A1, m + 4, 0); aR[m][1] = LDA(A1, m + 4, 1); }
    __builtin_amdgcn_sched_barrier(0);
    stage(t0 + 3, 0);
    SBAR;
    __builtin_amdgcn_s_setprio(1);
    #pragma unroll
    for (int m = 0; m < 4; m++)
      #pragma unroll
      for (int n = 0; n < 2; n++)
        #pragma unroll
        for (int kk = 0; kk < 2; kk++) acc[m + 4][n] = MF(aR[m][kk], bA[n][kk], acc[m + 4][n]);
    __builtin_amdgcn_s_setprio(0);
    SBAR;
    stage(t0 + 3, 1);
    SBAR;
    __builtin_amdgcn_s_setprio(1);
    #pragma unroll
    for (int m = 0; m < 4; m++)
      #pragma unroll
      for (int n = 0; n < 2; n++)
        #pragma unroll
        for (int kk = 0; kk < 2; kk++) acc[m + 4][n + 2] = MF(aR[m][kk], bB[n][kk], acc[m + 4][n + 2]);
    __builtin_amdgcn_s_setprio(0);
    asm volatile("s_waitcnt vmcnt(4)" ::: "memory");
    SBAR;
  }

  #pragma unroll
  for (int m = 0; m < 8; m++){
    int row = bm + wm * 128 + m * 16 + hi * 4;
    #pragma unroll
    for (int n = 0; n < 4; n++){
      int col = bn + wn * 64 + n * 16 + l15;
      float bv = bias[col];
      #pragma unroll
      for (int j = 0; j < 4; j++){
        float v = acc[m][n][j] + bv;
        if (EPI == 1){
          // exact-GELU via tanh form (max abs err ~3e-4)
          float w2 = v * v;
          float t = exp2f(v * fmaf(w2, 0.10294322f, 2.3022078f));
          float r = __builtin_amdgcn_rcpf(1.f + t);
          v = v - v * r;
        }
        ((unsigned short*)C)[(size_t)(row + j) * N + col] = f2bf(v);
      }
    }
  }
}

// ---------------- 128x128 GEMM, 4 waves, 64x64/wave (0.5 ds_read per MFMA) ----------------
// LDS-read-BW is the binding resource for the small GEMMs: acc[4][4] per wave gives
// 16 ds_read_b128 per 32 MFMA (vs 1.0/MFMA in all prior variants). 2-deep counted
// vmcnt(8), bm-per-XCD grouping (ideal 57 MB HBM traffic). EPI 2: fp32 + resid.
template<int EPI>
__global__ __launch_bounds__(256) void gemm4w128(
    const unsigned short* __restrict__ A,
    const unsigned short* __restrict__ B,
    const float* __restrict__ bias,
    const float* __restrict__ resid,
    void* __restrict__ C,
    int M, int N, int K)
{
  __shared__ __attribute__((aligned(16))) short As[2][128 * 64];
  __shared__ __attribute__((aligned(16))) short Bs[2][128 * 64];
  const int NT = K >> 6;
  int tid = threadIdx.x, lane = tid & 63, wave = tid >> 6;
  int wm = wave >> 1, wn = wave & 1;
  int l15 = lane & 15, hi = lane >> 4, l7 = l15 & 7;
  int lin = blockIdx.y * 8 + blockIdx.x;
  int xcd = lin & 7, idx = lin >> 3;
  int bm = (xcd * 4 + (idx >> 3)) * 128;   // 4 bm-panels per XCD (A-chunk 4 MB)
  int bn = (idx & 7) * 128;
  int lr = lane >> 3;
  int sega = ((lane & 7) ^ lr) * 8;
  f32x4 acc[4][4] = {};

  auto stage = [&](int buf, int k0){
    #pragma unroll
    for (int j = 0; j < 4; j++){
      int row = wave * 32 + j * 8;
      GL16(A + (size_t)(bm + row + lr) * K + k0 + sega, &As[buf][row * 64]);
      GL16(B + (size_t)(bn + row + lr) * K + k0 + sega, &Bs[buf][row * 64]);
    }
  };
  auto LDA = [&](int buf, int m, int kk){
    int R = wm * 64 + m * 16 + l15;
    return *(const short8*)(&As[buf][R * 64 + (((kk << 2) | hi) ^ l7) * 8]);
  };
  auto LDB = [&](int buf, int n, int kk){
    int R = wn * 64 + n * 16 + l15;
    return *(const short8*)(&Bs[buf][R * 64 + (((kk << 2) | hi) ^ l7) * 8]);
  };

  stage(0, 0);
  for (int t = 0; t < NT; t++){
    int cur = t & 1;
    if (t + 1 < NT){
      stage(cur ^ 1, (t + 1) << 6);
      asm volatile("s_waitcnt vmcnt(8)" ::: "memory");
    } else {
      asm volatile("s_waitcnt vmcnt(0)" ::: "memory");
    }
    SBAR;
    #pragma unroll
    for (int kk = 0; kk < 2; kk++){
      short8 af[4], bf[4];
      #pragma unroll
      for (int m = 0; m < 4; m++) af[m] = LDA(cur, m, kk);
      #pragma unroll
      for (int n = 0; n < 4; n++) bf[n] = LDB(cur, n, kk);
      __builtin_amdgcn_s_setprio(1);
      #pragma unroll
      for (int m = 0; m < 4; m++)
        #pragma unroll
        for (int n = 0; n < 4; n++)
          acc[m][n] = MF(af[m], bf[n], acc[m][n]);
      __builtin_amdgcn_s_setprio(0);
    }
    SBAR;
  }
  #pragma unroll
  for (int m = 0; m < 4; m++){
    int row = bm + wm * 64 + m * 16 + hi * 4;
    #pragma unroll
    for (int n = 0; n < 4; n++){
      int col = bn + wn * 64 + n * 16 + l15;
      float bv = bias[col];
      #pragma unroll
      for (int j = 0; j < 4; j++){
        float v = acc[m][n][j] + bv;
        int r = row + j;
        if (EPI == 2){
          ((float*)C)[(size_t)r * N + col] = v + resid[(size_t)r * N + col];
        } else {
          ((unsigned short*)C)[(size_t)r * N + col] = f2bf(v);
        }
      }
    }
  }
}

// ---------------- Flash attention: 8 waves, QBLK=128, balanced staging ----------------
__global__ __launch_bounds__(512) void attn_fwd(const unsigned short* __restrict__ qkv,
                                                unsigned short* __restrict__ o){
  __shared__ __attribute__((aligned(16))) short K_lds[2][64*64];
  __shared__ __attribute__((aligned(16))) short V_lds[2][64*64];   // V^T
  __shared__ __attribute__((aligned(16))) short P_lds[8][16*64];
  int tid = threadIdx.x, wave = tid >> 6, lane = tid & 63;
  int l15 = lane & 15, hi = lane >> 4, l7 = l15 & 7;
  int bid = blockIdx.x;
  int swz = (bid & 7) * 64 + (bid >> 3);
  int qt = swz & 15, bh = swz >> 4;
  int b = bh >> 4, h = bh & 15;
  const unsigned short* qbase = qkv + (size_t)b * 2048 * 3072 + h * 64;
  const unsigned short* kbase = qbase + 1024;
  const unsigned short* vbase = qbase + 2048;
  int qrow = qt * 128 + wave * 16 + l15;
  short8 qf0 = *(const short8*)(qbase + (size_t)qrow * 3072 + hi * 8);
  short8 qf1 = *(const short8*)(qbase + (size_t)qrow * 3072 + 32 + hi * 8);
  #pragma unroll
  for (int j = 0; j < 8; j++){
    float q0 = __uint_as_float((unsigned)(unsigned short)qf0[j] << 16) * 0.18033688f;
    float q1 = __uint_as_float((unsigned)(unsigned short)qf1[j] << 16) * 0.18033688f;
    qf0[j] = (short)f2bf(q0);
    qf1[j] = (short)f2bf(q1);
  }
  short8 ones8;
  #pragma unroll
  for (int j = 0; j < 8; j++) ones8[j] = (short)0x3F80;   // bf16 1.0
  int vt = tid - 256;
  int ki0 = tid * 2, ki1 = ki0 + 1;
  int kr0 = ki0 >> 3, ks0 = ki0 & 7;
  int kr1 = ki1 >> 3, ks1 = ki1 & 7;
  int kp = vt & 31, ds8 = (vt >> 5) & 7;
  int vcg = kp >> 2, vwi = (2 * kp) & 7;
  f32x4 accO[4] = {};
  f32x4 lacc = {};
  short* Pw = &P_lds[wave][0];

  auto kv_load = [&](int kt, short8& s0, short8& s1){
    if (vt < 0){
      s0 = *(const short8*)(kbase + (size_t)(kt + kr0) * 3072 + ks0 * 8);
      s1 = *(const short8*)(kbase + (size_t)(kt + kr1) * 3072 + ks1 * 8);
    } else {
      const unsigned short* vr = vbase + (size_t)(kt + 2 * kp) * 3072 + ds8 * 8;
      s0 = *(const short8*)vr;
      s1 = *(const short8*)(vr + 3072);
    }
  };
  auto kv_store = [&](int buf, short8 s0, short8 s1){
    if (vt < 0){
      *(short8*)(&K_lds[buf][kr0 * 64 + ((ks0 ^ (kr0 & 7)) << 3)]) = s0;
      *(short8*)(&K_lds[buf][kr1 * 64 + ((ks1 ^ (kr1 & 7)) << 3)]) = s1;
    } else {
      unsigned* Vw = (unsigned*)&V_lds[buf][0];
      #pragma unroll
      for (int j = 0; j < 8; j++){
        int d = ds8 * 8 + j;
        int sa = d * 64 + ((vcg ^ (d & 7)) << 3) + vwi;
        Vw[sa >> 1] = (unsigned)(unsigned short)s0[j] | ((unsigned)(unsigned short)s1[j] << 16);
      }
    }
  };

  {
    short8 s0, s1;
    kv_load(0, s0, s1);
    kv_store(0, s0, s1);
    __syncthreads();
  }

  for (int t = 0; t < 32; t++){
    int cur = t & 1;
    const short* Kc = &K_lds[cur][0];
    const short* Vc = &V_lds[cur][0];
    short8 s0, s1;
    if (t < 31) kv_load((t + 1) * 64, s0, s1);
    f32x4 sacc[4];
    __builtin_amdgcn_s_setprio(1);
    #pragma unroll
    for (int kb = 0; kb < 4; kb++){
      f32x4 s = {};
      short8 ka = *(const short8*)(Kc + (kb * 16 + l15) * 64 + ((hi ^ l7) << 3));
      s = __builtin_amdgcn_mfma_f32_16x16x32_bf16(ka, qf0, s, 0, 0, 0);
      short8 kb_ = *(const short8*)(Kc + (kb * 16 + l15) * 64 + (((4 + hi) ^ l7) << 3));
      s = __builtin_amdgcn_mfma_f32_16x16x32_bf16(kb_, qf1, s, 0, 0, 0);
      sacc[kb] = s;
    }
    __builtin_amdgcn_s_setprio(0);
    unsigned pu[8];
    #pragma unroll
    for (int kb = 0; kb < 4; kb++){
      unsigned u0 = (unsigned)(int)fmaf(sacc[kb][0], 128.f, 16248.6f);
      unsigned u1 = (unsigned)(int)fmaf(sacc[kb][1], 128.f, 16248.6f);
      unsigned u2 = (unsigned)(int)fmaf(sacc[kb][2], 128.f, 16248.6f);
      unsigned u3 = (unsigned)(int)fmaf(sacc[kb][3], 128.f, 16248.6f);
      pu[kb * 2]     = u0 | (u1 << 16);
      pu[kb * 2 + 1] = u2 | (u3 << 16);
    }
    #pragma unroll
    for (int kb = 0; kb < 4; kb++){
      int sa = l15 * 64 + ((((kb << 1) | (hi >> 1)) ^ l7) << 3) + ((hi & 1) << 2);
      *(uint2*)(Pw + sa) = make_uint2(pu[kb * 2], pu[kb * 2 + 1]);
    }
    __builtin_amdgcn_s_setprio(1);
    #pragma unroll
    for (int kb2 = 0; kb2 < 2; kb2++){
      short8 pf = *(const short8*)(Pw + l15 * 64 + ((((kb2 << 2) | hi) ^ l7) << 3));
      #pragma unroll
      for (int db = 0; db < 4; db++){
        short8 vf = *(const short8*)(Vc + (db * 16 + l15) * 64 + ((((kb2 << 2) | hi) ^ l7) << 3));
        accO[db] = __builtin_amdgcn_mfma_f32_16x16x32_bf16(vf, pf, accO[db], 0, 0, 0);
      }
      lacc = __builtin_amdgcn_mfma_f32_16x16x32_bf16(ones8, pf, lacc, 0, 0, 0);
    }
    __builtin_amdgcn_s_setprio(0);
    if (t < 31){
      kv_store(cur ^ 1, s0, s1);
      __syncthreads();
    }
  }
  float inv = 1.f / lacc[0];   // every lane holds l[q=l15] in all 4 regs
  unsigned short* ob = o + (size_t)(b * 2048 + qt * 128 + wave * 16 + l15) * 1024 + h * 64;
  #pragma unroll
  for (int db = 0; db < 4; db++){
    ushort4 w;
    w.x = f2bf(accO[db][0] * inv);
    w.y = f2bf(accO[db][1] * inv);
    w.z = f2bf(accO[db][2] * inv);
    w.w = f2bf(accO[db][3] * inv);
    *(ushort4*)(ob + db * 16 + hi * 4) = w;
  }
}

extern "C" void kernel_launch(void* const* d_in, const int* in_sizes, int n_in,
                              void* d_out, int out_size, void* d_ws, size_t ws_size,
                              hipStream_t stream){
  const float* x      = (const float*)d_in[0];
  const float* ln1_g  = (const float*)d_in[1];
  const float* ln1_b  = (const float*)d_in[2];
  const float* w_qkv  = (const float*)d_in[3];
  const float* b_qkv  = (const float*)d_in[4];
  const float* w_proj = (const float*)d_in[5];
  const float* b_proj = (const float*)d_in[6];
  const float* ln2_g  = (const float*)d_in[7];
  const float* ln2_b  = (const float*)d_in[8];
  const float* w_fc1  = (const float*)d_in[9];
  const float* b_fc1  = (const float*)d_in[10];
  const float* w_fc2  = (const float*)d_in[11];
  const float* b_fc2  = (const float*)d_in[12];
  float* out = (float*)d_out;
  char* ws = (char*)d_ws;
  const size_t MB = 1024 * 1024;
  unsigned short* h     = (unsigned short*)(ws);            // 8 MB  [4096,1024] bf16
  unsigned short* qkv   = (unsigned short*)(ws + 8*MB);     // 24 MB [4096,3072] bf16
  unsigned short* ob    = (unsigned short*)(ws + 32*MB);    // 8 MB  [4096,1024] bf16
  float*          x1    = (float*)(ws + 40*MB);             // 16 MB [4096,1024] fp32
  unsigned short* f     = (unsigned short*)(ws + 56*MB);    // 32 MB [4096,4096] bf16
  unsigned short* wqkvb = (unsigned short*)(ws + 88*MB);    // 6 MB
  unsigned short* wprojb= (unsigned short*)(ws + 94*MB);    // 2 MB
  unsigned short* wfc1b = (unsigned short*)(ws + 96*MB);    // 8 MB
  unsigned short* wfc2b = (unsigned short*)(ws + 104*MB);   // 8 MB

  cvt_all<<<12288, 256, 0, stream>>>(w_qkv, w_proj, w_fc1, w_fc2,
                                     wqkvb, wprojb, wfc1b, wfc2b);

  ln_bf16<<<4096, 256, 0, stream>>>(x, ln1_g, ln1_b, h);
  gemm8p<0><<<dim3(12, 16), 512, 0, stream>>>(h, wqkvb, b_qkv, qkv, 4096, 3072, 1024);
  attn_fwd<<<512, 512, 0, stream>>>(qkv, ob);
  gemm4w128<2><<<dim3(8, 32), 256, 0, stream>>>(ob, wprojb, b_proj, x, x1, 4096, 1024, 1024);
  ln_bf16<<<4096, 256, 0, stream>>>(x1, ln2_g, ln2_b, h);
  gemm8p<1><<<dim3(16, 16), 512, 0, stream>>>(h, wfc1b, b_fc1, f, 4096, 4096, 1024);
  gemm4w128<2><<<dim3(8, 32), 256, 0, stream>>>(f, wfc2b, b_fc2, x1, out, 4096, 1024, 4096);
}

// Round 15
// 220.410 us; speedup vs baseline: 1.1021x; 1.1021x over previous
//
#include <hip/hip_runtime.h>

typedef __attribute__((ext_vector_type(8))) short short8;
typedef __attribute__((ext_vector_type(4))) float f32x4;

static __device__ __forceinline__ unsigned short f2bf(float f){
  unsigned u = __float_as_uint(f);
  u += 0x7FFF + ((u >> 16) & 1);
  return (unsigned short)(u >> 16);
}

static __device__ __forceinline__ f32x4 MF(short8 a, short8 b, f32x4 c){
  return __builtin_amdgcn_mfma_f32_16x16x32_bf16(a, b, c, 0, 0, 0);
}

#define GL16(g, l) __builtin_amdgcn_global_load_lds( \
    (const __attribute__((address_space(1))) void*)(g), \
    (__attribute__((address_space(3))) void*)(l), 16, 0, 0)

#define SBAR { __builtin_amdgcn_sched_barrier(0); __builtin_amdgcn_s_barrier(); __builtin_amdgcn_sched_barrier(0); }

// ---------------- fp32 -> bf16 convert (all 4 weights, one launch) ----------------
__global__ __launch_bounds__(256) void cvt_all(
    const float* __restrict__ a0, const float* __restrict__ a1,
    const float* __restrict__ a2, const float* __restrict__ a3,
    unsigned short* __restrict__ o0, unsigned short* __restrict__ o1,
    unsigned short* __restrict__ o2, unsigned short* __restrict__ o3){
  int i = blockIdx.x * 256 + threadIdx.x;
  const float* src; unsigned short* dst; int off;
  if (i < 786432)       { src = a0; dst = o0; off = i; }
  else if (i < 1048576) { src = a1; dst = o1; off = i - 786432; }
  else if (i < 2097152) { src = a2; dst = o2; off = i - 1048576; }
  else                  { src = a3; dst = o3; off = i - 2097152; }
  float4 v = reinterpret_cast<const float4*>(src)[off];
  ushort4 o;
  o.x = f2bf(v.x); o.y = f2bf(v.y); o.z = f2bf(v.z); o.w = f2bf(v.w);
  reinterpret_cast<ushort4*>(dst)[off] = o;
}

// ---------------- LayerNorm fp32 -> bf16 ----------------
__global__ __launch_bounds__(256) void ln_bf16(const float* __restrict__ x,
    const float* __restrict__ g, const float* __restrict__ b,
    unsigned short* __restrict__ out){
  int row = blockIdx.x, t = threadIdx.x;
  const float* xr = x + (size_t)row * 1024;
  float4 xv = reinterpret_cast<const float4*>(xr)[t];
  float s  = xv.x + xv.y + xv.z + xv.w;
  float sq = xv.x*xv.x + xv.y*xv.y + xv.z*xv.z + xv.w*xv.w;
  #pragma unroll
  for (int m = 32; m >= 1; m >>= 1){ s += __shfl_xor(s, m); sq += __shfl_xor(sq, m); }
  __shared__ float ss[4], ssq[4];
  int w = t >> 6, lane = t & 63;
  if (lane == 0){ ss[w] = s; ssq[w] = sq; }
  __syncthreads();
  s  = ss[0] + ss[1] + ss[2] + ss[3];
  sq = ssq[0] + ssq[1] + ssq[2] + ssq[3];
  float mu = s * (1.f/1024.f);
  float rs = rsqrtf(sq * (1.f/1024.f) - mu*mu + 1e-5f);
  float4 gv = reinterpret_cast<const float4*>(g)[t];
  float4 bv = reinterpret_cast<const float4*>(b)[t];
  ushort4 o;
  o.x = f2bf((xv.x - mu) * rs * gv.x + bv.x);
  o.y = f2bf((xv.y - mu) * rs * gv.y + bv.y);
  o.z = f2bf((xv.z - mu) * rs * gv.z + bv.z);
  o.w = f2bf((xv.w - mu) * rs * gv.w + bv.w);
  reinterpret_cast<ushort4*>(out + (size_t)row * 1024)[t] = o;
}

// ---------------- 256x256 8-phase GEMM (m201 template, plain HIP) ----------------
template<int EPI>
__global__ __launch_bounds__(512, 2) void gemm8p(
    const unsigned short* __restrict__ A,
    const unsigned short* __restrict__ B,
    const float* __restrict__ bias,
    void* __restrict__ C,
    int M, int N, int K)
{
  __shared__ __attribute__((aligned(16))) short As[2 * 256 * 64];
  __shared__ __attribute__((aligned(16))) short Bs[2 * 256 * 64];
  const int NT = K >> 6;
  int tid = threadIdx.x, lane = tid & 63, wave = tid >> 6;
  int wm = wave >> 2, wn = wave & 3;
  int l15 = lane & 15, hi = lane >> 4;
  int hi2 = hi ^ (((l15 >> 2) & 1) << 1);
  int bm = blockIdx.y * 256, bn = blockIdx.x * 256;
  int lr = lane >> 3;
  int sg8 = ((lane & 7) ^ ((lane >> 5) << 1)) * 8;
  int rb0 = wave * 16;

  f32x4 acc[8][4] = {};
  short8 aR[4][2], bA[2][2], bB[2][2];

  auto stage = [&](int T, int h){
    if (T >= NT) return;
    const unsigned short* src = (h < 2) ? (A + (size_t)(bm + ((h & 1) << 7)) * K)
                                        : (B + (size_t)(bn + ((h & 1) << 7)) * K);
    short* dst = ((h < 2) ? As : Bs) + ((T & 1) << 14) + ((h & 1) << 13);
    const unsigned short* s = src + (size_t)(rb0 + lr) * K + (T << 6) + sg8;
    GL16(s, dst + rb0 * 64);
    GL16(s + (size_t)8 * K, dst + (rb0 + 8) * 64);
  };
  auto LDA = [&](const short* Ab, int m, int kk){
    int R = wm * 128 + m * 16 + l15;
    return *(const short8*)(Ab + R * 64 + kk * 32 + hi2 * 8);
  };
  auto LDB = [&](const short* Bb, int n, int kk){
    int R = wn * 64 + n * 16 + l15;
    return *(const short8*)(Bb + R * 64 + kk * 32 + hi2 * 8);
  };

  stage(0, 0); stage(0, 1); stage(0, 2); stage(0, 3);
  stage(1, 0); stage(1, 1);
  asm volatile("s_waitcnt vmcnt(4)" ::: "memory");
  SBAR;

  for (int i = 0; i < (NT >> 1); ++i){
    int t0 = 2 * i, t1 = t0 + 1;
    const short* A0 = As;            const short* B0 = Bs;
    const short* A1 = As + 16384;    const short* B1 = Bs + 16384;
    #pragma unroll
    for (int m = 0; m < 4; m++){ aR[m][0] = LDA(A0, m, 0); aR[m][1] = LDA(A0, m, 1); }
    #pragma unroll
    for (int n = 0; n < 2; n++){ bA[n][0] = LDB(B0, n, 0); bA[n][1] = LDB(B0, n, 1); }
    __builtin_amdgcn_sched_barrier(0);
    stage(t1, 2);
    SBAR;
    __builtin_amdgcn_s_setprio(1);
    #pragma unroll
    for (int m = 0; m < 4; m++)
      #pragma unroll
      for (int n = 0; n < 2; n++)
        #pragma unroll
        for (int kk = 0; kk < 2; kk++) acc[m][n] = MF(aR[m][kk], bA[n][kk], acc[m][n]);
    __builtin_amdgcn_s_setprio(0);
    SBAR;
    #pragma unroll
    for (int n = 0; n < 2; n++){ bB[n][0] = LDB(B0, n + 2, 0); bB[n][1] = LDB(B0, n + 2, 1); }
    __builtin_amdgcn_sched_barrier(0);
    stage(t1, 3);
    SBAR;
    __builtin_amdgcn_s_setprio(1);
    #pragma unroll
    for (int m = 0; m < 4; m++)
      #pragma unroll
      for (int n = 0; n < 2; n++)
        #pragma unroll
        for (int kk = 0; kk < 2; kk++) acc[m][n + 2] = MF(aR[m][kk], bB[n][kk], acc[m][n + 2]);
    __builtin_amdgcn_s_setprio(0);
    SBAR;
    #pragma unroll
    for (int m = 0; m < 4; m++){ aR[m][0] = LDA(A0, m + 4, 0); aR[m][1] = LDA(A0, m + 4, 1); }
    __builtin_amdgcn_sched_barrier(0);
    stage(t0 + 2, 0);
    SBAR;
    __builtin_amdgcn_s_setprio(1);
    #pragma unroll
    for (int m = 0; m < 4; m++)
      #pragma unroll
      for (int n = 0; n < 2; n++)
        #pragma unroll
        for (int kk = 0; kk < 2; kk++) acc[m + 4][n] = MF(aR[m][kk], bA[n][kk], acc[m + 4][n]);
    __builtin_amdgcn_s_setprio(0);
    SBAR;
    stage(t0 + 2, 1);
    SBAR;
    __builtin_amdgcn_s_setprio(1);
    #pragma unroll
    for (int m = 0; m < 4; m++)
      #pragma unroll
      for (int n = 0; n < 2; n++)
        #pragma unroll
        for (int kk = 0; kk < 2; kk++) acc[m + 4][n + 2] = MF(aR[m][kk], bB[n][kk], acc[m + 4][n + 2]);
    __builtin_amdgcn_s_setprio(0);
    asm volatile("s_waitcnt vmcnt(4)" ::: "memory");
    SBAR;
    #pragma unroll
    for (int m = 0; m < 4; m++){ aR[m][0] = LDA(A1, m, 0); aR[m][1] = LDA(A1, m, 1); }
    #pragma unroll
    for (int n = 0; n < 2; n++){ bA[n][0] = LDB(B1, n, 0); bA[n][1] = LDB(B1, n, 1); }
    __builtin_amdgcn_sched_barrier(0);
    stage(t0 + 2, 2);
    SBAR;
    __builtin_amdgcn_s_setprio(1);
    #pragma unroll
    for (int m = 0; m < 4; m++)
      #pragma unroll
      for (int n = 0; n < 2; n++)
        #pragma unroll
        for (int kk = 0; kk < 2; kk++) acc[m][n] = MF(aR[m][kk], bA[n][kk], acc[m][n]);
    __builtin_amdgcn_s_setprio(0);
    SBAR;
    #pragma unroll
    for (int n = 0; n < 2; n++){ bB[n][0] = LDB(B1, n + 2, 0); bB[n][1] = LDB(B1, n + 2, 1); }
    __builtin_amdgcn_sched_barrier(0);
    stage(t0 + 2, 3);
    SBAR;
    __builtin_amdgcn_s_setprio(1);
    #pragma unroll
    for (int m = 0; m < 4; m++)
      #pragma unroll
      for (int n = 0; n < 2; n++)
        #pragma unroll
        for (int kk = 0; kk < 2; kk++) acc[m][n + 2] = MF(aR[m][kk], bB[n][kk], acc[m][n + 2]);
    __builtin_amdgcn_s_setprio(0);
    SBAR;
    #pragma unroll
    for (int m = 0; m < 4; m++){ aR[m][0] = LDA(A1, m + 4, 0); aR[m][1] = LDA(A1, m + 4, 1); }
    __builtin_amdgcn_sched_barrier(0);
    stage(t0 + 3, 0);
    SBAR;
    __builtin_amdgcn_s_setprio(1);
    #pragma unroll
    for (int m = 0; m < 4; m++)
      #pragma unroll
      for (int n = 0; n < 2; n++)
        #pragma unroll
        for (int kk = 0; kk < 2; kk++) acc[m + 4][n] = MF(aR[m][kk], bA[n][kk], acc[m + 4][n]);
    __builtin_amdgcn_s_setprio(0);
    SBAR;
    stage(t0 + 3, 1);
    SBAR;
    __builtin_amdgcn_s_setprio(1);
    #pragma unroll
    for (int m = 0; m < 4; m++)
      #pragma unroll
      for (int n = 0; n < 2; n++)
        #pragma unroll
        for (int kk = 0; kk < 2; kk++) acc[m + 4][n + 2] = MF(aR[m][kk], bB[n][kk], acc[m + 4][n + 2]);
    __builtin_amdgcn_s_setprio(0);
    asm volatile("s_waitcnt vmcnt(4)" ::: "memory");
    SBAR;
  }

  #pragma unroll
  for (int m = 0; m < 8; m++){
    int row = bm + wm * 128 + m * 16 + hi * 4;
    #pragma unroll
    for (int n = 0; n < 4; n++){
      int col = bn + wn * 64 + n * 16 + l15;
      float bv = bias[col];
      #pragma unroll
      for (int j = 0; j < 4; j++){
        float v = acc[m][n][j] + bv;
        if (EPI == 1){
          // exact-GELU via tanh form (max abs err ~3e-4)
          float w2 = v * v;
          float t = exp2f(v * fmaf(w2, 0.10294322f, 2.3022078f));
          float r = __builtin_amdgcn_rcpf(1.f + t);
          v = v - v * r;
        }
        ((unsigned short*)C)[(size_t)(row + j) * N + col] = f2bf(v);
      }
    }
  }
}

// ---------------- 128x128 GEMM, 8 waves = 4 spatial (64x64) x 2 k-groups ----------------
// Intra-block split-K: kgroup kg handles K-tiles at j*128 + kg*64 with its own
// double-buffer. Wave-tile 64x64 -> 32 FLOP per LDS byte (2x the 32x32 variants)
// while keeping 8 waves/block for latency hiding. Epilogue: kg=1 partials merged
// via one 64 KB LDS pass. 8 GL16/thread/stage -> counted vmcnt(8). bm-per-XCD.
// EPI 2: fp32 out + residual add.
template<int EPI>
__global__ __launch_bounds__(512) void gemm_ks(
    const unsigned short* __restrict__ A,
    const unsigned short* __restrict__ B,
    const float* __restrict__ bias,
    const float* __restrict__ resid,
    void* __restrict__ C,
    int M, int N, int K)
{
  __shared__ __attribute__((aligned(16))) short As[2][2][128 * 64];  // [kg][dbuf]
  __shared__ __attribute__((aligned(16))) short Bs[2][2][128 * 64];
  const int NS = K >> 7;                    // super-iters (128 of K each)
  int tid = threadIdx.x, lane = tid & 63, wave = tid >> 6;
  int kg = wave >> 2;                       // k-group 0/1
  int ws = wave & 3;                        // spatial wave
  int wm = ws >> 1, wn = ws & 1;
  int l15 = lane & 15, hi = lane >> 4, l7 = l15 & 7;
  int lin = blockIdx.y * 8 + blockIdx.x;
  int xcd = lin & 7, idx = lin >> 3;
  int bm = (xcd * 4 + (idx >> 3)) * 128;    // 4 bm-panels per XCD
  int bn = (idx & 7) * 128;
  int lr = lane >> 3;
  int sega = ((lane & 7) ^ lr) * 8;
  f32x4 acc[4][4] = {};

  auto stage = [&](int buf, int k0){        // my kgroup's tile at global k0
    #pragma unroll
    for (int j = 0; j < 4; j++){
      int row = ws * 32 + j * 8;
      GL16(A + (size_t)(bm + row + lr) * K + k0 + sega, &As[kg][buf][row * 64]);
      GL16(B + (size_t)(bn + row + lr) * K + k0 + sega, &Bs[kg][buf][row * 64]);
    }
  };
  auto LDA = [&](int buf, int m, int kk){
    int R = wm * 64 + m * 16 + l15;
    return *(const short8*)(&As[kg][buf][R * 64 + (((kk << 2) | hi) ^ l7) * 8]);
  };
  auto LDB = [&](int buf, int n, int kk){
    int R = wn * 64 + n * 16 + l15;
    return *(const short8*)(&Bs[kg][buf][R * 64 + (((kk << 2) | hi) ^ l7) * 8]);
  };

  stage(0, kg * 64);
  for (int j = 0; j < NS; j++){
    int cur = j & 1;
    if (j + 1 < NS){
      stage(cur ^ 1, (j + 1) * 128 + kg * 64);
      asm volatile("s_waitcnt vmcnt(8)" ::: "memory");
    } else {
      asm volatile("s_waitcnt vmcnt(0)" ::: "memory");
    }
    SBAR;
    #pragma unroll
    for (int kk = 0; kk < 2; kk++){
      short8 af[4], bf[4];
      #pragma unroll
      for (int m = 0; m < 4; m++) af[m] = LDA(cur, m, kk);
      #pragma unroll
      for (int n = 0; n < 4; n++) bf[n] = LDB(cur, n, kk);
      __builtin_amdgcn_s_setprio(1);
      #pragma unroll
      for (int m = 0; m < 4; m++)
        #pragma unroll
        for (int n = 0; n < 4; n++)
          acc[m][n] = MF(af[m], bf[n], acc[m][n]);
      __builtin_amdgcn_s_setprio(0);
    }
    SBAR;
  }

  // merge kg=1 partials into kg=0 via LDS (reuse As: 4 waves x 16 KB = 64 KB)
  float* red = (float*)&As[0][0][0];
  if (kg == 1){
    #pragma unroll
    for (int m = 0; m < 4; m++)
      #pragma unroll
      for (int n = 0; n < 4; n++)
        #pragma unroll
        for (int j = 0; j < 4; j++)
          red[ws * 4096 + (m * 16 + hi * 4 + j) * 64 + n * 16 + l15] = acc[m][n][j];
  }
  __syncthreads();
  if (kg == 0){
    #pragma unroll
    for (int m = 0; m < 4; m++){
      int row = bm + wm * 64 + m * 16 + hi * 4;
      #pragma unroll
      for (int n = 0; n < 4; n++){
        int col = bn + wn * 64 + n * 16 + l15;
        float bv = bias[col];
        #pragma unroll
        for (int j = 0; j < 4; j++){
          float v = acc[m][n][j] + red[ws * 4096 + (m * 16 + hi * 4 + j) * 64 + n * 16 + l15] + bv;
          int r = row + j;
          if (EPI == 2){
            ((float*)C)[(size_t)r * N + col] = v + resid[(size_t)r * N + col];
          } else {
            ((unsigned short*)C)[(size_t)r * N + col] = f2bf(v);
          }
        }
      }
    }
  }
}

// ---------------- Flash attention: 8 waves, QBLK=128, balanced staging ----------------
__global__ __launch_bounds__(512) void attn_fwd(const unsigned short* __restrict__ qkv,
                                                unsigned short* __restrict__ o){
  __shared__ __attribute__((aligned(16))) short K_lds[2][64*64];
  __shared__ __attribute__((aligned(16))) short V_lds[2][64*64];   // V^T
  __shared__ __attribute__((aligned(16))) short P_lds[8][16*64];
  int tid = threadIdx.x, wave = tid >> 6, lane = tid & 63;
  int l15 = lane & 15, hi = lane >> 4, l7 = l15 & 7;
  int bid = blockIdx.x;
  int swz = (bid & 7) * 64 + (bid >> 3);
  int qt = swz & 15, bh = swz >> 4;
  int b = bh >> 4, h = bh & 15;
  const unsigned short* qbase = qkv + (size_t)b * 2048 * 3072 + h * 64;
  const unsigned short* kbase = qbase + 1024;
  const unsigned short* vbase = qbase + 2048;
  int qrow = qt * 128 + wave * 16 + l15;
  short8 qf0 = *(const short8*)(qbase + (size_t)qrow * 3072 + hi * 8);
  short8 qf1 = *(const short8*)(qbase + (size_t)qrow * 3072 + 32 + hi * 8);
  #pragma unroll
  for (int j = 0; j < 8; j++){
    float q0 = __uint_as_float((unsigned)(unsigned short)qf0[j] << 16) * 0.18033688f;
    float q1 = __uint_as_float((unsigned)(unsigned short)qf1[j] << 16) * 0.18033688f;
    qf0[j] = (short)f2bf(q0);
    qf1[j] = (short)f2bf(q1);
  }
  short8 ones8;
  #pragma unroll
  for (int j = 0; j < 8; j++) ones8[j] = (short)0x3F80;   // bf16 1.0
  int vt = tid - 256;
  int ki0 = tid * 2, ki1 = ki0 + 1;
  int kr0 = ki0 >> 3, ks0 = ki0 & 7;
  int kr1 = ki1 >> 3, ks1 = ki1 & 7;
  int kp = vt & 31, ds8 = (vt >> 5) & 7;
  int vcg = kp >> 2, vwi = (2 * kp) & 7;
  f32x4 accO[4] = {};
  f32x4 lacc = {};
  short* Pw = &P_lds[wave][0];

  auto kv_load = [&](int kt, short8& s0, short8& s1){
    if (vt < 0){
      s0 = *(const short8*)(kbase + (size_t)(kt + kr0) * 3072 + ks0 * 8);
      s1 = *(const short8*)(kbase + (size_t)(kt + kr1) * 3072 + ks1 * 8);
    } else {
      const unsigned short* vr = vbase + (size_t)(kt + 2 * kp) * 3072 + ds8 * 8;
      s0 = *(const short8*)vr;
      s1 = *(const short8*)(vr + 3072);
    }
  };
  auto kv_store = [&](int buf, short8 s0, short8 s1){
    if (vt < 0){
      *(short8*)(&K_lds[buf][kr0 * 64 + ((ks0 ^ (kr0 & 7)) << 3)]) = s0;
      *(short8*)(&K_lds[buf][kr1 * 64 + ((ks1 ^ (kr1 & 7)) << 3)]) = s1;
    } else {
      unsigned* Vw = (unsigned*)&V_lds[buf][0];
      #pragma unroll
      for (int j = 0; j < 8; j++){
        int d = ds8 * 8 + j;
        int sa = d * 64 + ((vcg ^ (d & 7)) << 3) + vwi;
        Vw[sa >> 1] = (unsigned)(unsigned short)s0[j] | ((unsigned)(unsigned short)s1[j] << 16);
      }
    }
  };

  {
    short8 s0, s1;
    kv_load(0, s0, s1);
    kv_store(0, s0, s1);
    __syncthreads();
  }

  for (int t = 0; t < 32; t++){
    int cur = t & 1;
    const short* Kc = &K_lds[cur][0];
    const short* Vc = &V_lds[cur][0];
    short8 s0, s1;
    if (t < 31) kv_load((t + 1) * 64, s0, s1);
    f32x4 sacc[4];
    __builtin_amdgcn_s_setprio(1);
    #pragma unroll
    for (int kb = 0; kb < 4; kb++){
      f32x4 s = {};
      short8 ka = *(const short8*)(Kc + (kb * 16 + l15) * 64 + ((hi ^ l7) << 3));
      s = __builtin_amdgcn_mfma_f32_16x16x32_bf16(ka, qf0, s, 0, 0, 0);
      short8 kb_ = *(const short8*)(Kc + (kb * 16 + l15) * 64 + (((4 + hi) ^ l7) << 3));
      s = __builtin_amdgcn_mfma_f32_16x16x32_bf16(kb_, qf1, s, 0, 0, 0);
      sacc[kb] = s;
    }
    __builtin_amdgcn_s_setprio(0);
    unsigned pu[8];
    #pragma unroll
    for (int kb = 0; kb < 4; kb++){
      unsigned u0 = (unsigned)(int)fmaf(sacc[kb][0], 128.f, 16248.6f);
      unsigned u1 = (unsigned)(int)fmaf(sacc[kb][1], 128.f, 16248.6f);
      unsigned u2 = (unsigned)(int)fmaf(sacc[kb][2], 128.f, 16248.6f);
      unsigned u3 = (unsigned)(int)fmaf(sacc[kb][3], 128.f, 16248.6f);
      pu[kb * 2]     = u0 | (u1 << 16);
      pu[kb * 2 + 1] = u2 | (u3 << 16);
    }
    #pragma unroll
    for (int kb = 0; kb < 4; kb++){
      int sa = l15 * 64 + ((((kb << 1) | (hi >> 1)) ^ l7) << 3) + ((hi & 1) << 2);
      *(uint2*)(Pw + sa) = make_uint2(pu[kb * 2], pu[kb * 2 + 1]);
    }
    __builtin_amdgcn_s_setprio(1);
    #pragma unroll
    for (int kb2 = 0; kb2 < 2; kb2++){
      short8 pf = *(const short8*)(Pw + l15 * 64 + ((((kb2 << 2) | hi) ^ l7) << 3));
      #pragma unroll
      for (int db = 0; db < 4; db++){
        short8 vf = *(const short8*)(Vc + (db * 16 + l15) * 64 + ((((kb2 << 2) | hi) ^ l7) << 3));
        accO[db] = __builtin_amdgcn_mfma_f32_16x16x32_bf16(vf, pf, accO[db], 0, 0, 0);
      }
      lacc = __builtin_amdgcn_mfma_f32_16x16x32_bf16(ones8, pf, lacc, 0, 0, 0);
    }
    __builtin_amdgcn_s_setprio(0);
    if (t < 31){
      kv_store(cur ^ 1, s0, s1);
      __syncthreads();
    }
  }
  float inv = 1.f / lacc[0];   // every lane holds l[q=l15] in all 4 regs
  unsigned short* ob = o + (size_t)(b * 2048 + qt * 128 + wave * 16 + l15) * 1024 + h * 64;
  #pragma unroll
  for (int db = 0; db < 4; db++){
    ushort4 w;
    w.x = f2bf(accO[db][0] * inv);
    w.y = f2bf(accO[db][1] * inv);
    w.z = f2bf(accO[db][2] * inv);
    w.w = f2bf(accO[db][3] * inv);
    *(ushort4*)(ob + db * 16 + hi * 4) = w;
  }
}

extern "C" void kernel_launch(void* const* d_in, const int* in_sizes, int n_in,
                              void* d_out, int out_size, void* d_ws, size_t ws_size,
                              hipStream_t stream){
  const float* x      = (const float*)d_in[0];
  const float* ln1_g  = (const float*)d_in[1];
  const float* ln1_b  = (const float*)d_in[2];
  const float* w_qkv  = (const float*)d_in[3];
  const float* b_qkv  = (const float*)d_in[4];
  const float* w_proj = (const float*)d_in[5];
  const float* b_proj = (const float*)d_in[6];
  const float* ln2_g  = (const float*)d_in[7];
  const float* ln2_b  = (const float*)d_in[8];
  const float* w_fc1  = (const float*)d_in[9];
  const float* b_fc1  = (const float*)d_in[10];
  const float* w_fc2  = (const float*)d_in[11];
  const float* b_fc2  = (const float*)d_in[12];
  float* out = (float*)d_out;
  char* ws = (char*)d_ws;
  const size_t MB = 1024 * 1024;
  unsigned short* h     = (unsigned short*)(ws);            // 8 MB  [4096,1024] bf16
  unsigned short* qkv   = (unsigned short*)(ws + 8*MB);     // 24 MB [4096,3072] bf16
  unsigned short* ob    = (unsigned short*)(ws + 32*MB);    // 8 MB  [4096,1024] bf16
  float*          x1    = (float*)(ws + 40*MB);             // 16 MB [4096,1024] fp32
  unsigned short* f     = (unsigned short*)(ws + 56*MB);    // 32 MB [4096,4096] bf16
  unsigned short* wqkvb = (unsigned short*)(ws + 88*MB);    // 6 MB
  unsigned short* wprojb= (unsigned short*)(ws + 94*MB);    // 2 MB
  unsigned short* wfc1b = (unsigned short*)(ws + 96*MB);    // 8 MB
  unsigned short* wfc2b = (unsigned short*)(ws + 104*MB);   // 8 MB

  cvt_all<<<12288, 256, 0, stream>>>(w_qkv, w_proj, w_fc1, w_fc2,
                                     wqkvb, wprojb, wfc1b, wfc2b);

  ln_bf16<<<4096, 256, 0, stream>>>(x, ln1_g, ln1_b, h);
  gemm8p<0><<<dim3(12, 16), 512, 0, stream>>>(h, wqkvb, b_qkv, qkv, 4096, 3072, 1024);
  attn_fwd<<<512, 512, 0, stream>>>(qkv, ob);
  gemm_ks<2><<<dim3(8, 32), 512, 0, stream>>>(ob, wprojb, b_proj, x, x1, 4096, 1024, 1024);
  ln_bf16<<<4096, 256, 0, stream>>>(x1, ln2_g, ln2_b, h);
  gemm8p<1><<<dim3(16, 16), 512, 0, stream>>>(h, wfc1b, b_fc1, f, 4096, 4096, 1024);
  gemm_ks<2><<<dim3(8, 32), 512, 0, stream>>>(f, wfc2b, b_fc2, x1, out, 4096, 1024, 4096);
}